// Round 3
// baseline (462.324 us; speedup 1.0000x reference)
//
#include <hip/hip_runtime.h>

// Problem sizes (fixed): B=32, T=256, D=512
#define B_ 32
#define T_ 256
#define D_ 512
#define L_ (T_ * T_)   // 65536, LayerNorm length

// ---------------------------------------------------------------- zero
__global__ __launch_bounds__(256) void zero_kernel(float* __restrict__ p, int n) {
  int i = blockIdx.x * 256 + threadIdx.x;
  if (i < n) p[i] = 0.f;
}

// ---------------------------------------------------------------- EMA (both passes fused)
// e1[t] = a1*x[t] + (1-a1)*e1[t-1], e1[0]=x[0]
// e2[t] = a2*e1[t] + (1-a2)*e2[t-1], e2[0]=e1[0]
// e = e1 + e2
__global__ __launch_bounds__(256) void ema2_kernel(const float* __restrict__ x,
                                                   float* __restrict__ e) {
  const int idx = blockIdx.x * 256 + threadIdx.x;  // b*D + d, 16384 total
  const double a1d = 0.9, a2d = 0.9 * 1.5;
  const float a1 = (float)a1d, o1 = (float)(1.0 - a1d);
  const float a2 = (float)a2d, o2 = (float)(1.0 - a2d);
  const size_t base = (size_t)(idx >> 9) * (T_ * D_) + (idx & (D_ - 1));
  const float* xp = x + base;
  float* ep = e + base;
  float c1 = xp[0];
  float c2 = c1;
  ep[0] = c1 + c2;
#pragma unroll 8
  for (int t = 1; t < T_; ++t) {
    float xv = xp[(size_t)t * D_];
    c1 = a1 * xv + o1 * c1;
    c2 = a2 * c1 + o2 * c2;
    ep[(size_t)t * D_] = c1 + c2;
  }
}

// ---------------------------------------------------------------- generic tiled f32 GEMM
// C[M,N] = act(A[M,K] @ B[K,N] + bias[N]); ACT: 0=tanh, 1=relu, 2=identity
template <int ACT>
__global__ __launch_bounds__(256) void gemm_bias_act(const float* __restrict__ A,
                                                     const float* __restrict__ Bm,
                                                     const float* __restrict__ bias,
                                                     float* __restrict__ C,
                                                     int M, int N, int K) {
  __shared__ float As[16][68];  // [k][m], padded
  __shared__ float Bs[16][68];  // [k][n], padded
  const int tid = threadIdx.x;
  const int tx = tid & 15;   // col group (4 cols each)
  const int ty = tid >> 4;   // row group (4 rows each)
  const int rowBase = blockIdx.y * 64;
  const int colBase = blockIdx.x * 64;

  float acc[4][4] = {};

  for (int k0 = 0; k0 < K; k0 += 16) {
    // stage A tile (64 rows x 16 k): thread -> row=t/4, kk=(t%4)*4, float4
    {
      const int r = tid >> 2;
      const int kk = (tid & 3) << 2;
      const float4 av =
          *reinterpret_cast<const float4*>(&A[(size_t)(rowBase + r) * K + k0 + kk]);
      As[kk + 0][r] = av.x;
      As[kk + 1][r] = av.y;
      As[kk + 2][r] = av.z;
      As[kk + 3][r] = av.w;
    }
    // stage B tile (16 k x 64 n): thread -> kk=t/16, n=(t%16)*4, float4
    {
      const int kk = tid >> 4;
      const int n = (tid & 15) << 2;
      const float4 bv =
          *reinterpret_cast<const float4*>(&Bm[(size_t)(k0 + kk) * N + colBase + n]);
      *reinterpret_cast<float4*>(&Bs[kk][n]) = bv;
    }
    __syncthreads();
#pragma unroll
    for (int kk = 0; kk < 16; ++kk) {
      float a[4], b[4];
      *reinterpret_cast<float4*>(a) = *reinterpret_cast<const float4*>(&As[kk][ty << 2]);
      *reinterpret_cast<float4*>(b) = *reinterpret_cast<const float4*>(&Bs[kk][tx << 2]);
#pragma unroll
      for (int i = 0; i < 4; ++i)
#pragma unroll
        for (int j = 0; j < 4; ++j) acc[i][j] = fmaf(a[i], b[j], acc[i][j]);
    }
    __syncthreads();
  }

#pragma unroll
  for (int i = 0; i < 4; ++i) {
    const size_t r = rowBase + (ty << 2) + i;
#pragma unroll
    for (int j = 0; j < 4; ++j) {
      const int c = colBase + (tx << 2) + j;
      float v = acc[i][j] + bias[c];
      if (ACT == 0) v = tanhf(v);
      if (ACT == 1) v = fmaxf(v, 0.f);
      C[r * N + c] = v;
    }
  }
}

// ---------------------------------------------------------------- LayerNorm stats (per b over 65536)
__global__ __launch_bounds__(256) void ln_stats_kernel(const float* __restrict__ f,
                                                       float* __restrict__ stats) {
  const int b = blockIdx.x;
  const float4* fp = reinterpret_cast<const float4*>(f + (size_t)b * L_);
  float s = 0.f, s2 = 0.f;
  for (int i = threadIdx.x; i < L_ / 4; i += 256) {
    float4 v = fp[i];
    s += v.x + v.y + v.z + v.w;
    s2 += v.x * v.x + v.y * v.y + v.z * v.z + v.w * v.w;
  }
#pragma unroll
  for (int off = 32; off; off >>= 1) {
    s += __shfl_down(s, off, 64);
    s2 += __shfl_down(s2, off, 64);
  }
  __shared__ float ls[4], ls2[4];
  const int wid = threadIdx.x >> 6, lane = threadIdx.x & 63;
  if (lane == 0) { ls[wid] = s; ls2[wid] = s2; }
  __syncthreads();
  if (threadIdx.x == 0) {
    const float S = ls[0] + ls[1] + ls[2] + ls[3];
    const float S2 = ls2[0] + ls2[1] + ls2[2] + ls2[3];
    const float mu = S / L_;
    const float var = S2 / L_ - mu * mu;
    stats[b * 2 + 0] = mu;
    stats[b * 2 + 1] = rsqrtf(var + 1e-3f);
  }
}

// ---------------------------------------------------------------- Wa GEMM (split-K, LN fused in staging)
// acc[b, n] += sum_k LN(f[b,k]) * Wa[k, n]
#define WA_KC 2048  // K-range per block
#define WA_KS 512   // K staged in LDS at a time
__global__ __launch_bounds__(256) void wa_gemm_kernel(const float* __restrict__ f,
                                                      const float* __restrict__ Wa,
                                                      const float* __restrict__ gamma,
                                                      const float* __restrict__ beta,
                                                      const float* __restrict__ stats,
                                                      float* __restrict__ acc) {
  const int k0 = blockIdx.x * WA_KC;
  const int n0 = blockIdx.y * 64;
  const int tid = threadIdx.x;
  const int ci = tid & 63;  // column within n-range
  const int kg = tid >> 6;  // k subgroup (0..3)
  __shared__ float fs[B_ * WA_KS];  // 64 KB, [b][kk]

  float accr[B_];
#pragma unroll
  for (int b = 0; b < B_; ++b) accr[b] = 0.f;

  for (int s = 0; s < WA_KC; s += WA_KS) {
    // stage f chunk with LayerNorm applied; coalesced in 512-float runs
    for (int l = tid; l < B_ * WA_KS; l += 256) {
      const int b = l >> 9;
      const int kk = l & (WA_KS - 1);
      const int gk = k0 + s + kk;
      const float mu = stats[b * 2 + 0], rs = stats[b * 2 + 1];
      const float v = f[(size_t)b * L_ + gk];
      fs[l] = (v - mu) * rs * gamma[gk] + beta[gk];
    }
    __syncthreads();
    // each kg owns kk in {kg*4 + 16*m .. +3}; float4 broadcast LDS reads
    for (int kk4 = kg << 2; kk4 < WA_KS; kk4 += 16) {
      float w[4];
#pragma unroll
      for (int j = 0; j < 4; ++j)
        w[j] = Wa[(size_t)(k0 + s + kk4 + j) * T_ + n0 + ci];
#pragma unroll
      for (int b = 0; b < B_; ++b) {
        const float4 fv = *reinterpret_cast<const float4*>(&fs[b * WA_KS + kk4]);
        accr[b] = fmaf(fv.x, w[0],
                  fmaf(fv.y, w[1], fmaf(fv.z, w[2], fmaf(fv.w, w[3], accr[b]))));
      }
    }
    __syncthreads();
  }

  // reduce the 4 kg partials via LDS (reuse fs), then atomicAdd
  float* red = fs;  // 256*33 floats = 33 KB <= 64 KB
#pragma unroll
  for (int b = 0; b < B_; ++b) red[tid * 33 + b] = accr[b];
  __syncthreads();
  if (kg == 0) {
#pragma unroll
    for (int b = 0; b < B_; ++b) {
      const float v = red[ci * 33 + b] + red[(ci + 64) * 33 + b] +
                      red[(ci + 128) * 33 + b] + red[(ci + 192) * 33 + b];
      atomicAdd(&acc[b * T_ + n0 + ci], v);
    }
  }
}

// ---------------------------------------------------------------- finalize: out = sigmoid(acc+ba) * x
__global__ __launch_bounds__(64) void finalize_kernel(const float* __restrict__ x,
                                                      const float* __restrict__ acc,
                                                      const float* __restrict__ ba,
                                                      float* __restrict__ out) {
  const int bt = blockIdx.x;       // b*T + t
  const int t = bt & (T_ - 1);
  const float a = acc[bt] + ba[t];
  const float sg = 1.f / (1.f + expf(-a));
  const float4* xp = reinterpret_cast<const float4*>(x + (size_t)bt * D_);
  float4* op = reinterpret_cast<float4*>(out + (size_t)bt * D_);
#pragma unroll
  for (int i = 0; i < 2; ++i) {
    float4 v = xp[threadIdx.x + i * 64];
    v.x *= sg; v.y *= sg; v.z *= sg; v.w *= sg;
    op[threadIdx.x + i * 64] = v;
  }
}

// ---------------------------------------------------------------- launch
extern "C" void kernel_launch(void* const* d_in, const int* in_sizes, int n_in,
                              void* d_out, int out_size, void* d_ws, size_t ws_size,
                              hipStream_t stream) {
  const float* x     = (const float*)d_in[0];
  const float* W1    = (const float*)d_in[1];
  const float* b1    = (const float*)d_in[2];
  const float* W2    = (const float*)d_in[3];
  const float* b2    = (const float*)d_in[4];
  const float* W3    = (const float*)d_in[5];
  const float* b3    = (const float*)d_in[6];
  const float* gamma = (const float*)d_in[7];
  const float* beta  = (const float*)d_in[8];
  const float* Wa    = (const float*)d_in[9];
  const float* ba    = (const float*)d_in[10];
  float* out = (float*)d_out;

  char* ws = (char*)d_ws;
  // e aliases d_out (dead before the final write). ws: h1 | h2 | f | stats | acc
  float* e     = out;
  float* h1    = (float*)(ws + 0);
  float* h2    = (float*)(ws + 8388608);
  float* f     = (float*)(ws + 16777216);
  float* stats = (float*)(ws + 25165824);
  float* acc   = (float*)(ws + 25165824 + 1024);

  zero_kernel<<<(B_ * T_ + 255) / 256, 256, 0, stream>>>(acc, B_ * T_);
  ema2_kernel<<<(B_ * D_) / 256, 256, 0, stream>>>(x, e);
  // h1 = tanh(e @ W1 + b1)   [8192,512]x[512,256]
  gemm_bias_act<0><<<dim3(T_ / 64, (B_ * T_) / 64), 256, 0, stream>>>(e, W1, b1, h1,
                                                                      B_ * T_, T_, D_);
  // h2 = relu(h1 @ W2 + b2)  [8192,256]x[256,256]
  gemm_bias_act<1><<<dim3(T_ / 64, (B_ * T_) / 64), 256, 0, stream>>>(h1, W2, b2, h2,
                                                                      B_ * T_, T_, T_);
  // f = h2 @ W3 + b3         [8192,256]x[256,256]
  gemm_bias_act<2><<<dim3(T_ / 64, (B_ * T_) / 64), 256, 0, stream>>>(h2, W3, b3, f,
                                                                      B_ * T_, T_, T_);
  ln_stats_kernel<<<B_, 256, 0, stream>>>(f, stats);
  wa_gemm_kernel<<<dim3(L_ / WA_KC, T_ / 64), 256, 0, stream>>>(f, Wa, gamma, beta,
                                                                stats, acc);
  finalize_kernel<<<B_ * T_, 64, 0, stream>>>(x, acc, ba, out);
}

// Round 4
// 335.049 us; speedup vs baseline: 1.3799x; 1.3799x over previous
//
#include <hip/hip_runtime.h>
#include <hip/hip_bf16.h>

// Problem sizes (fixed): B=32, T=256, D=512
#define B_ 32
#define T_ 256
#define D_ 512
#define L_ (T_ * T_)   // 65536

typedef __attribute__((ext_vector_type(8))) short bf16x8;
typedef __attribute__((ext_vector_type(4))) float f32x4;

// ---------------- weight transpose + bf16 convert: W[K][N] f32 -> Wt[N][K] bf16
__global__ __launch_bounds__(256) void convert_wt(const float* __restrict__ W,
                                                  __hip_bfloat16* __restrict__ Wt,
                                                  int K, int N) {
  __shared__ float tile[32][33];
  const int k0 = blockIdx.y * 32, n0 = blockIdx.x * 32;
  const int c = threadIdx.x & 31, r = threadIdx.x >> 5;  // r = 0..7
#pragma unroll
  for (int i = 0; i < 32; i += 8)
    tile[r + i][c] = W[(size_t)(k0 + r + i) * N + n0 + c];
  __syncthreads();
#pragma unroll
  for (int i = 0; i < 32; i += 8)
    Wt[(size_t)(n0 + r + i) * K + k0 + c] = __float2bfloat16(tile[c][r + i]);
}

// ---------------- EMA (both passes fused), bf16 output
__global__ __launch_bounds__(256) void ema2_kernel(const float* __restrict__ x,
                                                   __hip_bfloat16* __restrict__ e) {
  const int idx = blockIdx.x * 256 + threadIdx.x;  // b*D + d
  const double a1d = 0.9, a2d = 0.9 * 1.5;
  const float a1 = (float)a1d, o1 = (float)(1.0 - a1d);
  const float a2 = (float)a2d, o2 = (float)(1.0 - a2d);
  const size_t base = (size_t)(idx >> 9) * (T_ * D_) + (idx & (D_ - 1));
  const float* xp = x + base;
  __hip_bfloat16* ep = e + base;
  float c1 = xp[0];
  float c2 = c1;
  ep[0] = __float2bfloat16(c1 + c2);
#pragma unroll 8
  for (int t = 1; t < T_; ++t) {
    float xv = xp[(size_t)t * D_];
    c1 = a1 * xv + o1 * c1;
    c2 = a2 * c1 + o2 * c2;
    ep[(size_t)t * D_] = __float2bfloat16(c1 + c2);
  }
}

// ---------------- bf16 MFMA GEMM: C = act(A[M,K] @ Bt[N,K]^T + bias)
// 128x128 tile, 4 waves (2x2) each 64x64 of 16x16x32 frags. m97 structure.
template <int K, int ACT, bool OUTBF16>
__global__ __launch_bounds__(256) void mfma_gemm(const __hip_bfloat16* __restrict__ A,
                                                 const __hip_bfloat16* __restrict__ Bt,
                                                 const float* __restrict__ bias,
                                                 void* __restrict__ Cout, int N) {
  __shared__ __align__(16) short As[128 * 32];  // [row][k] bf16
  __shared__ __align__(16) short Bs[128 * 32];  // [col][k] bf16
  const int tid = threadIdx.x;
  const int lane = tid & 63, w = tid >> 6;
  const int wr = w >> 1, wc = w & 1;
  const int rowBase = blockIdx.y * 128, colBase = blockIdx.x * 128;
  const int r = tid >> 2, kb = tid & 3;  // staging coords: 4 threads x 16B = 64B row

  const short* Ag = (const short*)A;
  const short* Bg = (const short*)Bt;

  f32x4 acc[4][4] = {};

  for (int k0 = 0; k0 < K; k0 += 32) {
    __builtin_amdgcn_global_load_lds(
        (const __attribute__((address_space(1))) void*)(Ag + (size_t)(rowBase + r) * K + k0 + kb * 8),
        (__attribute__((address_space(3))) void*)(As + w * 512), 16, 0, 0);
    __builtin_amdgcn_global_load_lds(
        (const __attribute__((address_space(1))) void*)(Ag + (size_t)(rowBase + 64 + r) * K + k0 + kb * 8),
        (__attribute__((address_space(3))) void*)(As + 2048 + w * 512), 16, 0, 0);
    __builtin_amdgcn_global_load_lds(
        (const __attribute__((address_space(1))) void*)(Bg + (size_t)(colBase + r) * K + k0 + kb * 8),
        (__attribute__((address_space(3))) void*)(Bs + w * 512), 16, 0, 0);
    __builtin_amdgcn_global_load_lds(
        (const __attribute__((address_space(1))) void*)(Bg + (size_t)(colBase + 64 + r) * K + k0 + kb * 8),
        (__attribute__((address_space(3))) void*)(Bs + 2048 + w * 512), 16, 0, 0);
    __syncthreads();  // drains vmcnt -> staged data visible

    bf16x8 af[4], bfr[4];
#pragma unroll
    for (int m = 0; m < 4; ++m)
      af[m] = *(const bf16x8*)&As[(wr * 64 + m * 16 + (lane & 15)) * 32 + (lane >> 4) * 8];
#pragma unroll
    for (int n = 0; n < 4; ++n)
      bfr[n] = *(const bf16x8*)&Bs[(wc * 64 + n * 16 + (lane & 15)) * 32 + (lane >> 4) * 8];
#pragma unroll
    for (int m = 0; m < 4; ++m)
#pragma unroll
      for (int n = 0; n < 4; ++n)
        acc[m][n] = __builtin_amdgcn_mfma_f32_16x16x32_bf16(af[m], bfr[n], acc[m][n], 0, 0, 0);
    __syncthreads();
  }

  // epilogue: C/D layout col=lane&15, row=(lane>>4)*4+reg (m89-verified)
  const int orow0 = rowBase + wr * 64 + ((lane >> 4) << 2);
  const int ocol0 = colBase + wc * 64 + (lane & 15);
#pragma unroll
  for (int m = 0; m < 4; ++m)
#pragma unroll
    for (int n = 0; n < 4; ++n) {
      const int gc = ocol0 + n * 16;
      const float bv = bias[gc];
#pragma unroll
      for (int j = 0; j < 4; ++j) {
        const size_t gr = orow0 + m * 16 + j;
        float v = acc[m][n][j] + bv;
        if (ACT == 0) v = tanhf(v);
        if (ACT == 1) v = fmaxf(v, 0.f);
        if (OUTBF16)
          ((__hip_bfloat16*)Cout)[gr * N + gc] = __float2bfloat16(v);
        else
          ((float*)Cout)[gr * N + gc] = v;
      }
    }
}

// ---------------- LayerNorm stats (per b over 65536)
__global__ __launch_bounds__(1024) void ln_stats_kernel(const float* __restrict__ f,
                                                        float* __restrict__ stats) {
  const int b = blockIdx.x;
  const f32x4* fp = (const f32x4*)(f + (size_t)b * L_);
  float s = 0.f, s2 = 0.f;
  for (int i = threadIdx.x; i < L_ / 4; i += 1024) {
    f32x4 v = fp[i];
    s += v.x + v.y + v.z + v.w;
    s2 += v.x * v.x + v.y * v.y + v.z * v.z + v.w * v.w;
  }
#pragma unroll
  for (int off = 32; off; off >>= 1) {
    s += __shfl_down(s, off, 64);
    s2 += __shfl_down(s2, off, 64);
  }
  __shared__ float ls[16], ls2[16];
  const int wid = threadIdx.x >> 6, lane = threadIdx.x & 63;
  if (lane == 0) { ls[wid] = s; ls2[wid] = s2; }
  __syncthreads();
  if (threadIdx.x == 0) {
    float S = 0.f, S2 = 0.f;
#pragma unroll
    for (int i = 0; i < 16; ++i) { S += ls[i]; S2 += ls2[i]; }
    const float mu = S / L_;
    const float var = S2 / L_ - mu * mu;
    stats[b * 2 + 0] = mu;
    stats[b * 2 + 1] = rsqrtf(var + 1e-3f);
  }
}

// ---------------- Wa GEMM: partial[kb][b][n] = sum_{k in chunk} LN(f[b,k]) * Wa[k,n]
// 256 blocks (k-chunks of 256), each covers ALL 256 n-cols. Wa streamed exactly once.
#define WKC 256
__global__ __launch_bounds__(256) void wa_gemm2(const float* __restrict__ f,
                                                const float* __restrict__ Wa,
                                                const float* __restrict__ gamma,
                                                const float* __restrict__ beta,
                                                const float* __restrict__ stats,
                                                float* __restrict__ partial) {
  const int kbidx = blockIdx.x;
  const int k0 = kbidx * WKC;
  const int tid = threadIdx.x, lane = tid & 63, w = tid >> 6;
  __shared__ float fs[WKC][36];  // [k][b], +4 pad keeps 16B alignment & spreads banks

  // stage LN'd f chunk, transposed
  for (int l = tid; l < B_ * WKC; l += 256) {
    const int b = l >> 8, kk = l & (WKC - 1);
    const int gk = k0 + kk;
    fs[kk][b] = (f[(size_t)b * L_ + gk] - stats[b * 2]) * stats[b * 2 + 1] * gamma[gk] + beta[gk];
  }
  __syncthreads();

  f32x4 acc[B_];
#pragma unroll
  for (int b = 0; b < B_; ++b) acc[b] = {0.f, 0.f, 0.f, 0.f};

  const int kbeg = w * 64;
  for (int kk = kbeg; kk < kbeg + 64; ++kk) {
    const f32x4 wv = *(const f32x4*)&Wa[(size_t)(k0 + kk) * T_ + lane * 4];  // coalesced 1KB/wave
    const float* fr = fs[kk];  // broadcast reads (b128-merged)
#pragma unroll
    for (int b = 0; b < B_; ++b) acc[b] += wv * fr[b];
  }

  // cross-wave reduce via LDS (reuse fs: 9216 floats >= 8192), 4 passes of 8 b's
  float* red = &fs[0][0];
#pragma unroll
  for (int p = 0; p < 4; ++p) {
    __syncthreads();
#pragma unroll
    for (int b8 = 0; b8 < 8; ++b8)
      *(f32x4*)&red[(w * 8 + b8) * 256 + lane * 4] = acc[p * 8 + b8];
    __syncthreads();
#pragma unroll
    for (int i = 0; i < 8; ++i) {
      const int o = i * 256 + tid;  // o = b8*256 + n
      const int b8 = o >> 8, n = o & 255;
      const float s = red[(0 * 8 + b8) * 256 + n] + red[(1 * 8 + b8) * 256 + n] +
                      red[(2 * 8 + b8) * 256 + n] + red[(3 * 8 + b8) * 256 + n];
      partial[(size_t)kbidx * (B_ * T_) + (p * 8 + b8) * T_ + n] = s;
    }
  }
}

// ---------------- reduce partials over 256 k-chunks, fuse +ba and sigmoid -> g[b*T+t]
__global__ __launch_bounds__(256) void wa_reduce(const float* __restrict__ partial,
                                                 const float* __restrict__ ba,
                                                 float* __restrict__ g) {
  const int o0 = blockIdx.x * 32;  // 256 blocks x 32 outputs
  const int tid = threadIdx.x, lane = tid & 63, w = tid >> 6;
  const int oo = tid & 31;   // output within block
  const int kg = tid >> 5;   // 0..7: kb-group of 32
  float s = 0.f;
#pragma unroll 8
  for (int i = 0; i < 32; ++i)
    s += partial[(size_t)(kg * 32 + i) * (B_ * T_) + o0 + oo];
  s += __shfl_down(s, 32, 64);  // fold the two kg's within each wave
  __shared__ float red[4][32];
  if ((lane >> 5) == 0) red[w][oo] = s;
  __syncthreads();
  if (tid < 32) {
    float tot = red[0][tid] + red[1][tid] + red[2][tid] + red[3][tid];
    const int o = o0 + tid;
    tot += ba[o & (T_ - 1)];
    g[o] = 1.f / (1.f + __expf(-tot));
  }
}

// ---------------- finalize: out = g[bt] * x
__global__ __launch_bounds__(128) void finalize_kernel(const float* __restrict__ x,
                                                       const float* __restrict__ g,
                                                       float* __restrict__ out) {
  const int bt = blockIdx.x;
  const float sg = g[bt];
  const f32x4* xp = (const f32x4*)(x + (size_t)bt * D_);
  f32x4* op = (f32x4*)(out + (size_t)bt * D_);
  op[threadIdx.x] = xp[threadIdx.x] * sg;
}

// ---------------- launch
extern "C" void kernel_launch(void* const* d_in, const int* in_sizes, int n_in,
                              void* d_out, int out_size, void* d_ws, size_t ws_size,
                              hipStream_t stream) {
  const float* x     = (const float*)d_in[0];
  const float* W1    = (const float*)d_in[1];
  const float* b1    = (const float*)d_in[2];
  const float* W2    = (const float*)d_in[3];
  const float* b2    = (const float*)d_in[4];
  const float* W3    = (const float*)d_in[5];
  const float* b3    = (const float*)d_in[6];
  const float* gamma = (const float*)d_in[7];
  const float* beta  = (const float*)d_in[8];
  const float* Wa    = (const float*)d_in[9];
  const float* ba    = (const float*)d_in[10];
  float* out = (float*)d_out;

  char* ws = (char*)d_ws;
  // ws layout (17.33 MB total; known-safe <= 25.2 MB):
  __hip_bfloat16* h1  = (__hip_bfloat16*)(ws + 0);         // 4 MB
  __hip_bfloat16* h2  = (__hip_bfloat16*)(ws + 4194304);   // 4 MB
  float* f            = (float*)(ws + 8388608);            // 8.4 MB
  __hip_bfloat16* Wt1 = (__hip_bfloat16*)(ws + 16777216);  // 256 KB
  __hip_bfloat16* Wt2 = (__hip_bfloat16*)(ws + 17039360);  // 128 KB
  __hip_bfloat16* Wt3 = (__hip_bfloat16*)(ws + 17170432);  // 128 KB
  float* stats        = (float*)(ws + 17301504);           // 256 B
  float* g            = (float*)(ws + 17301760);           // 32 KB
  float* partial      = (float*)(ws + 0);                  // 8.39 MB, aliases h1+h2 (dead by then)
  __hip_bfloat16* e16 = (__hip_bfloat16*)d_out;            // 8 MB of the 16.8 MB out buf (dead before final write)

  convert_wt<<<dim3(T_ / 32, D_ / 32), 256, 0, stream>>>(W1, Wt1, D_, T_);
  convert_wt<<<dim3(T_ / 32, T_ / 32), 256, 0, stream>>>(W2, Wt2, T_, T_);
  convert_wt<<<dim3(T_ / 32, T_ / 32), 256, 0, stream>>>(W3, Wt3, T_, T_);
  ema2_kernel<<<(B_ * D_) / 256, 256, 0, stream>>>(x, e16);
  // h1 = tanh(e @ W1 + b1)
  mfma_gemm<D_, 0, true><<<dim3(T_ / 128, (B_ * T_) / 128), 256, 0, stream>>>(e16, Wt1, b1, h1, T_);
  // h2 = relu(h1 @ W2 + b2)
  mfma_gemm<T_, 1, true><<<dim3(T_ / 128, (B_ * T_) / 128), 256, 0, stream>>>(h1, Wt2, b2, h2, T_);
  // f = h2 @ W3 + b3  (f32 out, protects the K=65536 reduction)
  mfma_gemm<T_, 2, false><<<dim3(T_ / 128, (B_ * T_) / 128), 256, 0, stream>>>(h2, Wt3, b3, f, T_);
  ln_stats_kernel<<<B_, 1024, 0, stream>>>(f, stats);
  wa_gemm2<<<L_ / WKC, 256, 0, stream>>>(f, Wa, gamma, beta, stats, partial);
  wa_reduce<<<(B_ * T_) / 32, 256, 0, stream>>>(partial, ba, g);
  finalize_kernel<<<B_ * T_, 128, 0, stream>>>(x, g, out);
}

// Round 8
// 233.900 us; speedup vs baseline: 1.9766x; 1.4324x over previous
//
#include <hip/hip_runtime.h>
#include <hip/hip_bf16.h>

// Problem sizes (fixed): B=32, T=256, D=512
#define B_ 32
#define T_ 256
#define D_ 512
#define L_ (T_ * T_)   // 65536

typedef __attribute__((ext_vector_type(8))) short bf16x8;
typedef __attribute__((ext_vector_type(4))) float f32x4;

static __device__ __forceinline__ unsigned short f2bf(float f) {
  __hip_bfloat16 h = __float2bfloat16(f);
  return *reinterpret_cast<unsigned short*>(&h);
}

// ---------------- weight transpose + bf16 convert: W[K][N] f32 -> Wt[N][K] bf16
__global__ __launch_bounds__(256) void convert_wt(const float* __restrict__ W,
                                                  __hip_bfloat16* __restrict__ Wt,
                                                  int K, int N) {
  __shared__ float tile[32][33];
  const int k0 = blockIdx.y * 32, n0 = blockIdx.x * 32;
  const int c = threadIdx.x & 31, r = threadIdx.x >> 5;  // r = 0..7
#pragma unroll
  for (int i = 0; i < 32; i += 8)
    tile[r + i][c] = W[(size_t)(k0 + r + i) * N + n0 + c];
  __syncthreads();
#pragma unroll
  for (int i = 0; i < 32; i += 8)
    Wt[(size_t)(n0 + r + i) * K + k0 + c] = __float2bfloat16(tile[c][r + i]);
}

// ---------------- EMA (both passes fused), chunked-scan version, bf16 output
// Linear recurrence => carry influence decays as 0.1^k / 0.35^k. Each thread
// owns one (b, 32-t chunk, float4 d-group): 32 warm-up steps from zero carries
// (error <= 0.35^32 ~ 1e-15), then 32 live steps. Chunk 0 runs the exact init.
#define EMA_CH 32
__global__ __launch_bounds__(128) void ema2_kernel(const float* __restrict__ x,
                                                   __hip_bfloat16* __restrict__ e) {
  const int flat = blockIdx.x * 128 + threadIdx.x;  // 32768 threads
  const int d4 = flat & 127;          // float4 group within D
  const int ci = (flat >> 7) & 7;     // chunk index, 8 chunks of 32
  const int b = flat >> 10;
  const double a1d = 0.9, a2d = 0.9 * 1.5;
  const float a1 = (float)a1d, o1 = (float)(1.0 - a1d);
  const float a2 = (float)a2d, o2 = (float)(1.0 - a2d);

  const size_t base = (size_t)b * (T_ * D_) + (size_t)d4 * 4;
  const float* xp = x + base;
  __hip_bfloat16* ep = e + base;

  f32x4 c1, c2;
  const int t0 = ci * EMA_CH;
  int tstart;
  if (ci == 0) {
    const f32x4 xv = *(const f32x4*)xp;
    c1 = xv;
    c2 = xv;
    const f32x4 v = c1 + c2;
    short4 p;
    p.x = (short)f2bf(v.x); p.y = (short)f2bf(v.y);
    p.z = (short)f2bf(v.z); p.w = (short)f2bf(v.w);
    *(short4*)ep = p;
    tstart = 1;
  } else {
    c1 = (f32x4){0.f, 0.f, 0.f, 0.f};
    c2 = (f32x4){0.f, 0.f, 0.f, 0.f};
#pragma unroll 8
    for (int t = t0 - EMA_CH; t < t0; ++t) {  // warm-up, no store
      const f32x4 xv = *(const f32x4*)(xp + (size_t)t * D_);
      c1 = a1 * xv + o1 * c1;
      c2 = a2 * c1 + o2 * c2;
    }
    tstart = t0;
  }
#pragma unroll 8
  for (int t = tstart; t < t0 + EMA_CH; ++t) {  // live steps
    const f32x4 xv = *(const f32x4*)(xp + (size_t)t * D_);
    c1 = a1 * xv + o1 * c1;
    c2 = a2 * c1 + o2 * c2;
    const f32x4 v = c1 + c2;
    short4 p;
    p.x = (short)f2bf(v.x); p.y = (short)f2bf(v.y);
    p.z = (short)f2bf(v.z); p.w = (short)f2bf(v.w);
    *(short4*)(ep + (size_t)t * D_) = p;
  }
}

// ---------------- bf16 MFMA GEMM: C = act(A[M,K] @ Bt[N,K]^T + bias)
// 128x128 tile, 4 waves (2x2) each 64x64 of 16x16x32 frags. m97 structure.
template <int K, int ACT, bool OUTBF16>
__global__ __launch_bounds__(256) void mfma_gemm(const __hip_bfloat16* __restrict__ A,
                                                 const __hip_bfloat16* __restrict__ Bt,
                                                 const float* __restrict__ bias,
                                                 void* __restrict__ Cout, int N) {
  __shared__ __align__(16) short As[128 * 32];  // [row][k] bf16
  __shared__ __align__(16) short Bs[128 * 32];  // [col][k] bf16
  const int tid = threadIdx.x;
  const int lane = tid & 63, w = tid >> 6;
  const int wr = w >> 1, wc = w & 1;
  const int rowBase = blockIdx.y * 128, colBase = blockIdx.x * 128;
  const int r = tid >> 2, kb = tid & 3;  // staging coords: 4 threads x 16B = 64B row

  const short* Ag = (const short*)A;
  const short* Bg = (const short*)Bt;

  f32x4 acc[4][4] = {};

  for (int k0 = 0; k0 < K; k0 += 32) {
    __builtin_amdgcn_global_load_lds(
        (const __attribute__((address_space(1))) void*)(Ag + (size_t)(rowBase + r) * K + k0 + kb * 8),
        (__attribute__((address_space(3))) void*)(As + w * 512), 16, 0, 0);
    __builtin_amdgcn_global_load_lds(
        (const __attribute__((address_space(1))) void*)(Ag + (size_t)(rowBase + 64 + r) * K + k0 + kb * 8),
        (__attribute__((address_space(3))) void*)(As + 2048 + w * 512), 16, 0, 0);
    __builtin_amdgcn_global_load_lds(
        (const __attribute__((address_space(1))) void*)(Bg + (size_t)(colBase + r) * K + k0 + kb * 8),
        (__attribute__((address_space(3))) void*)(Bs + w * 512), 16, 0, 0);
    __builtin_amdgcn_global_load_lds(
        (const __attribute__((address_space(1))) void*)(Bg + (size_t)(colBase + 64 + r) * K + k0 + kb * 8),
        (__attribute__((address_space(3))) void*)(Bs + 2048 + w * 512), 16, 0, 0);
    __syncthreads();  // drains vmcnt -> staged data visible

    bf16x8 af[4], bfr[4];
#pragma unroll
    for (int m = 0; m < 4; ++m)
      af[m] = *(const bf16x8*)&As[(wr * 64 + m * 16 + (lane & 15)) * 32 + (lane >> 4) * 8];
#pragma unroll
    for (int n = 0; n < 4; ++n)
      bfr[n] = *(const bf16x8*)&Bs[(wc * 64 + n * 16 + (lane & 15)) * 32 + (lane >> 4) * 8];
#pragma unroll
    for (int m = 0; m < 4; ++m)
#pragma unroll
      for (int n = 0; n < 4; ++n)
        acc[m][n] = __builtin_amdgcn_mfma_f32_16x16x32_bf16(af[m], bfr[n], acc[m][n], 0, 0, 0);
    __syncthreads();
  }

  // epilogue: C/D layout col=lane&15, row=(lane>>4)*4+reg (m89-verified)
  const int orow0 = rowBase + wr * 64 + ((lane >> 4) << 2);
  const int ocol0 = colBase + wc * 64 + (lane & 15);
#pragma unroll
  for (int m = 0; m < 4; ++m)
#pragma unroll
    for (int n = 0; n < 4; ++n) {
      const int gc = ocol0 + n * 16;
      const float bv = bias[gc];
#pragma unroll
      for (int j = 0; j < 4; ++j) {
        const size_t gr = orow0 + m * 16 + j;
        float v = acc[m][n][j] + bv;
        if (ACT == 0) v = tanhf(v);
        if (ACT == 1) v = fmaxf(v, 0.f);
        if (OUTBF16)
          ((__hip_bfloat16*)Cout)[gr * N + gc] = __float2bfloat16(v);
        else
          ((float*)Cout)[gr * N + gc] = v;
      }
    }
}

// ---------------- LayerNorm stats (per b over 65536)
__global__ __launch_bounds__(1024) void ln_stats_kernel(const float* __restrict__ f,
                                                        float* __restrict__ stats) {
  const int b = blockIdx.x;
  const f32x4* fp = (const f32x4*)(f + (size_t)b * L_);
  float s = 0.f, s2 = 0.f;
  for (int i = threadIdx.x; i < L_ / 4; i += 1024) {
    f32x4 v = fp[i];
    s += v.x + v.y + v.z + v.w;
    s2 += v.x * v.x + v.y * v.y + v.z * v.z + v.w * v.w;
  }
#pragma unroll
  for (int off = 32; off; off >>= 1) {
    s += __shfl_down(s, off, 64);
    s2 += __shfl_down(s2, off, 64);
  }
  __shared__ float ls[16], ls2[16];
  const int wid = threadIdx.x >> 6, lane = threadIdx.x & 63;
  if (lane == 0) { ls[wid] = s; ls2[wid] = s2; }
  __syncthreads();
  if (threadIdx.x == 0) {
    float S = 0.f, S2 = 0.f;
#pragma unroll
    for (int i = 0; i < 16; ++i) { S += ls[i]; S2 += ls2[i]; }
    const float mu = S / L_;
    const float var = S2 / L_ - mu * mu;
    stats[b * 2 + 0] = mu;
    stats[b * 2 + 1] = rsqrtf(var + 1e-3f);
  }
}

// ---------------- Wa GEMM: partial[kb][b][n] = sum_{k in chunk} LN(f[b,k]) * Wa[k,n]
// 256 blocks (k-chunks of 256), each covers ALL 256 n-cols. Wa streamed exactly once.
#define WKC 256
__global__ __launch_bounds__(256) void wa_gemm2(const float* __restrict__ f,
                                                const float* __restrict__ Wa,
                                                const float* __restrict__ gamma,
                                                const float* __restrict__ beta,
                                                const float* __restrict__ stats,
                                                float* __restrict__ partial) {
  const int kbidx = blockIdx.x;
  const int k0 = kbidx * WKC;
  const int tid = threadIdx.x, lane = tid & 63, w = tid >> 6;
  __shared__ float fs[WKC][36];  // [k][b], +4 pad keeps 16B alignment & spreads banks

  // stage LN'd f chunk, transposed
  for (int l = tid; l < B_ * WKC; l += 256) {
    const int b = l >> 8, kk = l & (WKC - 1);
    const int gk = k0 + kk;
    fs[kk][b] = (f[(size_t)b * L_ + gk] - stats[b * 2]) * stats[b * 2 + 1] * gamma[gk] + beta[gk];
  }
  __syncthreads();

  f32x4 acc[B_];
#pragma unroll
  for (int b = 0; b < B_; ++b) acc[b] = {0.f, 0.f, 0.f, 0.f};

  const int kbeg = w * 64;
  for (int kk = kbeg; kk < kbeg + 64; ++kk) {
    const f32x4 wv = *(const f32x4*)&Wa[(size_t)(k0 + kk) * T_ + lane * 4];  // coalesced 1KB/wave
    const float* fr = fs[kk];  // broadcast reads (b128-merged)
#pragma unroll
    for (int b = 0; b < B_; ++b) acc[b] += wv * fr[b];
  }

  // cross-wave reduce via LDS (reuse fs: 9216 floats >= 8192), 4 passes of 8 b's
  float* red = &fs[0][0];
#pragma unroll
  for (int p = 0; p < 4; ++p) {
    __syncthreads();
#pragma unroll
    for (int b8 = 0; b8 < 8; ++b8)
      *(f32x4*)&red[(w * 8 + b8) * 256 + lane * 4] = acc[p * 8 + b8];
    __syncthreads();
#pragma unroll
    for (int i = 0; i < 8; ++i) {
      const int o = i * 256 + tid;  // o = b8*256 + n
      const int b8 = o >> 8, n = o & 255;
      const float s = red[(0 * 8 + b8) * 256 + n] + red[(1 * 8 + b8) * 256 + n] +
                      red[(2 * 8 + b8) * 256 + n] + red[(3 * 8 + b8) * 256 + n];
      partial[(size_t)kbidx * (B_ * T_) + (p * 8 + b8) * T_ + n] = s;
    }
  }
}

// ---------------- reduce partials over 256 k-chunks, fuse +ba and sigmoid -> g[b*T+t]
__global__ __launch_bounds__(256) void wa_reduce(const float* __restrict__ partial,
                                                 const float* __restrict__ ba,
                                                 float* __restrict__ g) {
  const int o0 = blockIdx.x * 32;  // 256 blocks x 32 outputs
  const int tid = threadIdx.x, lane = tid & 63, w = tid >> 6;
  const int oo = tid & 31;   // output within block
  const int kg = tid >> 5;   // 0..7: kb-group of 32
  float s = 0.f;
#pragma unroll 8
  for (int i = 0; i < 32; ++i)
    s += partial[(size_t)(kg * 32 + i) * (B_ * T_) + o0 + oo];
  s += __shfl_down(s, 32, 64);  // fold the two kg's within each wave
  __shared__ float red[4][32];
  if ((lane >> 5) == 0) red[w][oo] = s;
  __syncthreads();
  if (tid < 32) {
    float tot = red[0][tid] + red[1][tid] + red[2][tid] + red[3][tid];
    const int o = o0 + tid;
    tot += ba[o & (T_ - 1)];
    g[o] = 1.f / (1.f + __expf(-tot));
  }
}

// ---------------- finalize: out = g[bt] * x
__global__ __launch_bounds__(128) void finalize_kernel(const float* __restrict__ x,
                                                       const float* __restrict__ g,
                                                       float* __restrict__ out) {
  const int bt = blockIdx.x;
  const float sg = g[bt];
  const f32x4* xp = (const f32x4*)(x + (size_t)bt * D_);
  f32x4* op = (f32x4*)(out + (size_t)bt * D_);
  op[threadIdx.x] = xp[threadIdx.x] * sg;
}

// ---------------- launch
extern "C" void kernel_launch(void* const* d_in, const int* in_sizes, int n_in,
                              void* d_out, int out_size, void* d_ws, size_t ws_size,
                              hipStream_t stream) {
  const float* x     = (const float*)d_in[0];
  const float* W1    = (const float*)d_in[1];
  const float* b1    = (const float*)d_in[2];
  const float* W2    = (const float*)d_in[3];
  const float* b2    = (const float*)d_in[4];
  const float* W3    = (const float*)d_in[5];
  const float* b3    = (const float*)d_in[6];
  const float* gamma = (const float*)d_in[7];
  const float* beta  = (const float*)d_in[8];
  const float* Wa    = (const float*)d_in[9];
  const float* ba    = (const float*)d_in[10];
  float* out = (float*)d_out;

  char* ws = (char*)d_ws;
  // ws layout (17.33 MB total):
  __hip_bfloat16* h1  = (__hip_bfloat16*)(ws + 0);         // 4 MB
  __hip_bfloat16* h2  = (__hip_bfloat16*)(ws + 4194304);   // 4 MB
  float* f            = (float*)(ws + 8388608);            // 8.4 MB
  __hip_bfloat16* Wt1 = (__hip_bfloat16*)(ws + 16777216);  // 256 KB
  __hip_bfloat16* Wt2 = (__hip_bfloat16*)(ws + 17039360);  // 128 KB
  __hip_bfloat16* Wt3 = (__hip_bfloat16*)(ws + 17170432);  // 128 KB
  float* stats        = (float*)(ws + 17301504);           // 256 B
  float* g            = (float*)(ws + 17301760);           // 32 KB
  float* partial      = (float*)(ws + 0);                  // 8.39 MB, aliases h1+h2 (dead by then)
  __hip_bfloat16* e16 = (__hip_bfloat16*)d_out;            // 8 MB of the 16.8 MB out buf (dead before final write)

  convert_wt<<<dim3(T_ / 32, D_ / 32), 256, 0, stream>>>(W1, Wt1, D_, T_);
  convert_wt<<<dim3(T_ / 32, T_ / 32), 256, 0, stream>>>(W2, Wt2, T_, T_);
  convert_wt<<<dim3(T_ / 32, T_ / 32), 256, 0, stream>>>(W3, Wt3, T_, T_);
  ema2_kernel<<<(B_ * (T_ / EMA_CH) * (D_ / 4)) / 128, 128, 0, stream>>>(x, e16);
  // h1 = tanh(e @ W1 + b1)
  mfma_gemm<D_, 0, true><<<dim3(T_ / 128, (B_ * T_) / 128), 256, 0, stream>>>(e16, Wt1, b1, h1, T_);
  // h2 = relu(h1 @ W2 + b2)
  mfma_gemm<T_, 1, true><<<dim3(T_ / 128, (B_ * T_) / 128), 256, 0, stream>>>(h1, Wt2, b2, h2, T_);
  // f = h2 @ W3 + b3  (f32 out, protects the K=65536 reduction)
  mfma_gemm<T_, 2, false><<<dim3(T_ / 128, (B_ * T_) / 128), 256, 0, stream>>>(h2, Wt3, b3, f, T_);
  ln_stats_kernel<<<B_, 1024, 0, stream>>>(f, stats);
  wa_gemm2<<<L_ / WKC, 256, 0, stream>>>(f, Wa, gamma, beta, stats, partial);
  wa_reduce<<<(B_ * T_) / 32, 256, 0, stream>>>(partial, ba, g);
  finalize_kernel<<<B_ * T_, 128, 0, stream>>>(x, g, out);
}

// Round 9
// 226.795 us; speedup vs baseline: 2.0385x; 1.0313x over previous
//
#include <hip/hip_runtime.h>
#include <hip/hip_bf16.h>

// Problem sizes (fixed): B=32, T=256, D=512
#define B_ 32
#define T_ 256
#define D_ 512
#define L_ (T_ * T_)   // 65536

typedef __attribute__((ext_vector_type(8))) short bf16x8;
typedef __attribute__((ext_vector_type(4))) float f32x4;

static __device__ __forceinline__ unsigned short f2bf(float f) {
  __hip_bfloat16 h = __float2bfloat16(f);
  return *reinterpret_cast<unsigned short*>(&h);
}

// ---------------- weight transpose + bf16 convert: W[K][N] f32 -> Wt[N][K] bf16
__global__ __launch_bounds__(256) void convert_wt(const float* __restrict__ W,
                                                  __hip_bfloat16* __restrict__ Wt,
                                                  int K, int N) {
  __shared__ float tile[32][33];
  const int k0 = blockIdx.y * 32, n0 = blockIdx.x * 32;
  const int c = threadIdx.x & 31, r = threadIdx.x >> 5;  // r = 0..7
#pragma unroll
  for (int i = 0; i < 32; i += 8)
    tile[r + i][c] = W[(size_t)(k0 + r + i) * N + n0 + c];
  __syncthreads();
#pragma unroll
  for (int i = 0; i < 32; i += 8)
    Wt[(size_t)(n0 + r + i) * K + k0 + c] = __float2bfloat16(tile[c][r + i]);
}

// ---------------- EMA (both passes fused), chunked-scan version, bf16 output
#define EMA_CH 32
__global__ __launch_bounds__(128) void ema2_kernel(const float* __restrict__ x,
                                                   __hip_bfloat16* __restrict__ e) {
  const int flat = blockIdx.x * 128 + threadIdx.x;  // 32768 threads
  const int d4 = flat & 127;          // float4 group within D
  const int ci = (flat >> 7) & 7;     // chunk index, 8 chunks of 32
  const int b = flat >> 10;
  const double a1d = 0.9, a2d = 0.9 * 1.5;
  const float a1 = (float)a1d, o1 = (float)(1.0 - a1d);
  const float a2 = (float)a2d, o2 = (float)(1.0 - a2d);

  const size_t base = (size_t)b * (T_ * D_) + (size_t)d4 * 4;
  const float* xp = x + base;
  __hip_bfloat16* ep = e + base;

  f32x4 c1, c2;
  const int t0 = ci * EMA_CH;
  int tstart;
  if (ci == 0) {
    const f32x4 xv = *(const f32x4*)xp;
    c1 = xv;
    c2 = xv;
    const f32x4 v = c1 + c2;
    short4 p;
    p.x = (short)f2bf(v.x); p.y = (short)f2bf(v.y);
    p.z = (short)f2bf(v.z); p.w = (short)f2bf(v.w);
    *(short4*)ep = p;
    tstart = 1;
  } else {
    c1 = (f32x4){0.f, 0.f, 0.f, 0.f};
    c2 = (f32x4){0.f, 0.f, 0.f, 0.f};
#pragma unroll 8
    for (int t = t0 - EMA_CH; t < t0; ++t) {  // warm-up, no store
      const f32x4 xv = *(const f32x4*)(xp + (size_t)t * D_);
      c1 = a1 * xv + o1 * c1;
      c2 = a2 * c1 + o2 * c2;
    }
    tstart = t0;
  }
#pragma unroll 8
  for (int t = tstart; t < t0 + EMA_CH; ++t) {  // live steps
    const f32x4 xv = *(const f32x4*)(xp + (size_t)t * D_);
    c1 = a1 * xv + o1 * c1;
    c2 = a2 * c1 + o2 * c2;
    const f32x4 v = c1 + c2;
    short4 p;
    p.x = (short)f2bf(v.x); p.y = (short)f2bf(v.y);
    p.z = (short)f2bf(v.z); p.w = (short)f2bf(v.w);
    *(short4*)(ep + (size_t)t * D_) = p;
  }
}

// ---------------- bf16 MFMA GEMM: C = act(A[M,K] @ Bt[N,K]^T + bias)
template <int K, int ACT, bool OUTBF16>
__global__ __launch_bounds__(256) void mfma_gemm(const __hip_bfloat16* __restrict__ A,
                                                 const __hip_bfloat16* __restrict__ Bt,
                                                 const float* __restrict__ bias,
                                                 void* __restrict__ Cout, int N) {
  __shared__ __align__(16) short As[128 * 32];  // [row][k] bf16
  __shared__ __align__(16) short Bs[128 * 32];  // [col][k] bf16
  const int tid = threadIdx.x;
  const int lane = tid & 63, w = tid >> 6;
  const int wr = w >> 1, wc = w & 1;
  const int rowBase = blockIdx.y * 128, colBase = blockIdx.x * 128;
  const int r = tid >> 2, kb = tid & 3;  // staging coords: 4 threads x 16B = 64B row

  const short* Ag = (const short*)A;
  const short* Bg = (const short*)Bt;

  f32x4 acc[4][4] = {};

  for (int k0 = 0; k0 < K; k0 += 32) {
    __builtin_amdgcn_global_load_lds(
        (const __attribute__((address_space(1))) void*)(Ag + (size_t)(rowBase + r) * K + k0 + kb * 8),
        (__attribute__((address_space(3))) void*)(As + w * 512), 16, 0, 0);
    __builtin_amdgcn_global_load_lds(
        (const __attribute__((address_space(1))) void*)(Ag + (size_t)(rowBase + 64 + r) * K + k0 + kb * 8),
        (__attribute__((address_space(3))) void*)(As + 2048 + w * 512), 16, 0, 0);
    __builtin_amdgcn_global_load_lds(
        (const __attribute__((address_space(1))) void*)(Bg + (size_t)(colBase + r) * K + k0 + kb * 8),
        (__attribute__((address_space(3))) void*)(Bs + w * 512), 16, 0, 0);
    __builtin_amdgcn_global_load_lds(
        (const __attribute__((address_space(1))) void*)(Bg + (size_t)(colBase + 64 + r) * K + k0 + kb * 8),
        (__attribute__((address_space(3))) void*)(Bs + 2048 + w * 512), 16, 0, 0);
    __syncthreads();  // drains vmcnt -> staged data visible

    bf16x8 af[4], bfr[4];
#pragma unroll
    for (int m = 0; m < 4; ++m)
      af[m] = *(const bf16x8*)&As[(wr * 64 + m * 16 + (lane & 15)) * 32 + (lane >> 4) * 8];
#pragma unroll
    for (int n = 0; n < 4; ++n)
      bfr[n] = *(const bf16x8*)&Bs[(wc * 64 + n * 16 + (lane & 15)) * 32 + (lane >> 4) * 8];
#pragma unroll
    for (int m = 0; m < 4; ++m)
#pragma unroll
      for (int n = 0; n < 4; ++n)
        acc[m][n] = __builtin_amdgcn_mfma_f32_16x16x32_bf16(af[m], bfr[n], acc[m][n], 0, 0, 0);
    __syncthreads();
  }

  // epilogue: C/D layout col=lane&15, row=(lane>>4)*4+reg (m89-verified)
  const int orow0 = rowBase + wr * 64 + ((lane >> 4) << 2);
  const int ocol0 = colBase + wc * 64 + (lane & 15);
#pragma unroll
  for (int m = 0; m < 4; ++m)
#pragma unroll
    for (int n = 0; n < 4; ++n) {
      const int gc = ocol0 + n * 16;
      const float bv = bias[gc];
#pragma unroll
      for (int j = 0; j < 4; ++j) {
        const size_t gr = orow0 + m * 16 + j;
        float v = acc[m][n][j] + bv;
        if (ACT == 0) v = tanhf(v);
        if (ACT == 1) v = fmaxf(v, 0.f);
        if (OUTBF16)
          ((__hip_bfloat16*)Cout)[gr * N + gc] = __float2bfloat16(v);
        else
          ((float*)Cout)[gr * N + gc] = v;
      }
    }
}

// ---------------- LayerNorm stats (per b over 65536)
__global__ __launch_bounds__(1024) void ln_stats_kernel(const float* __restrict__ f,
                                                        float* __restrict__ stats) {
  const int b = blockIdx.x;
  const f32x4* fp = (const f32x4*)(f + (size_t)b * L_);
  float s = 0.f, s2 = 0.f;
  for (int i = threadIdx.x; i < L_ / 4; i += 1024) {
    f32x4 v = fp[i];
    s += v.x + v.y + v.z + v.w;
    s2 += v.x * v.x + v.y * v.y + v.z * v.z + v.w * v.w;
  }
#pragma unroll
  for (int off = 32; off; off >>= 1) {
    s += __shfl_down(s, off, 64);
    s2 += __shfl_down(s2, off, 64);
  }
  __shared__ float ls[16], ls2[16];
  const int wid = threadIdx.x >> 6, lane = threadIdx.x & 63;
  if (lane == 0) { ls[wid] = s; ls2[wid] = s2; }
  __syncthreads();
  if (threadIdx.x == 0) {
    float S = 0.f, S2 = 0.f;
#pragma unroll
    for (int i = 0; i < 16; ++i) { S += ls[i]; S2 += ls2[i]; }
    const float mu = S / L_;
    const float var = S2 / L_ - mu * mu;
    stats[b * 2 + 0] = mu;
    stats[b * 2 + 1] = rsqrtf(var + 1e-3f);
  }
}

// ---------------- Wa GEMM v3: latency fix for the 60us wa_gemm2.
// 256 blocks (k-chunks of 256) x 512 threads (8 waves). Wave (g=w&3, h=w>>2):
// b-group g (8 batches) x k-half h (128 k). acc shrinks 32->8 f32x4 (32 VGPR,
// stays in registers; old 128-VGPR acc showed VGPR_Count=84 => spill). k-loop
// unrolled x4 with preloaded Wa vectors for memory-level parallelism.
#define WKC 256
__global__ __launch_bounds__(512) void wa_gemm3(const float* __restrict__ f,
                                                const float* __restrict__ Wa,
                                                const float* __restrict__ gamma,
                                                const float* __restrict__ beta,
                                                const float* __restrict__ stats,
                                                float* __restrict__ partial) {
  const int kbidx = blockIdx.x;
  const int k0 = kbidx * WKC;
  const int tid = threadIdx.x, lane = tid & 63, w = tid >> 6;
  const int g = w & 3, h = w >> 2;  // b-group, k-half
  __shared__ float fs[WKC][36];     // 36 KB; stride 36 floats: b128-aligned at b0 multiples of 8

  // stage LN'd f chunk, transposed; coalesced 256-float runs per b
  for (int l = tid; l < B_ * WKC; l += 512) {
    const int b = l >> 8, kk = l & (WKC - 1);
    const int gk = k0 + kk;
    fs[kk][b] = (f[(size_t)b * L_ + gk] - stats[b * 2]) * stats[b * 2 + 1] * gamma[gk] + beta[gk];
  }
  __syncthreads();

  f32x4 acc[8] = {};
  const int b0 = g * 8;
  const size_t kbase = k0 + h * 128;
  for (int kk = 0; kk < 128; kk += 4) {
    f32x4 wv[4];
#pragma unroll
    for (int u = 0; u < 4; ++u)
      wv[u] = *(const f32x4*)&Wa[(kbase + kk + u) * T_ + lane * 4];  // 4 independent loads in flight
#pragma unroll
    for (int u = 0; u < 4; ++u) {
      const float* frow = &fs[h * 128 + kk + u][b0];
      const f32x4 fA = *(const f32x4*)frow;        // broadcast b128, conflict-free
      const f32x4 fB = *(const f32x4*)(frow + 4);
      acc[0] += wv[u] * fA.x; acc[1] += wv[u] * fA.y;
      acc[2] += wv[u] * fA.z; acc[3] += wv[u] * fA.w;
      acc[4] += wv[u] * fB.x; acc[5] += wv[u] * fB.y;
      acc[6] += wv[u] * fB.z; acc[7] += wv[u] * fB.w;
    }
  }

  // combine k-halves: h=1 parks in LDS (reusing fs: 9216 >= 8192 floats), h=0 adds+stores
  __syncthreads();
  float* red = &fs[0][0];
  if (h == 1) {
#pragma unroll
    for (int bb = 0; bb < 8; ++bb)
      *(f32x4*)&red[(size_t)(b0 + bb) * 256 + lane * 4] = acc[bb];
  }
  __syncthreads();
  if (h == 0) {
#pragma unroll
    for (int bb = 0; bb < 8; ++bb) {
      const f32x4 o = acc[bb] + *(const f32x4*)&red[(size_t)(b0 + bb) * 256 + lane * 4];
      *(f32x4*)&partial[(size_t)kbidx * (B_ * T_) + (size_t)(b0 + bb) * T_ + lane * 4] = o;
    }
  }
}

// ---------------- reduce partials over 256 k-chunks, fuse +ba and sigmoid -> g[b*T+t]
__global__ __launch_bounds__(256) void wa_reduce(const float* __restrict__ partial,
                                                 const float* __restrict__ ba,
                                                 float* __restrict__ g) {
  const int o0 = blockIdx.x * 32;  // 256 blocks x 32 outputs
  const int tid = threadIdx.x, lane = tid & 63, w = tid >> 6;
  const int oo = tid & 31;   // output within block
  const int kg = tid >> 5;   // 0..7: kb-group of 32
  float s = 0.f;
#pragma unroll 8
  for (int i = 0; i < 32; ++i)
    s += partial[(size_t)(kg * 32 + i) * (B_ * T_) + o0 + oo];
  s += __shfl_down(s, 32, 64);  // fold the two kg's within each wave
  __shared__ float red[4][32];
  if ((lane >> 5) == 0) red[w][oo] = s;
  __syncthreads();
  if (tid < 32) {
    float tot = red[0][tid] + red[1][tid] + red[2][tid] + red[3][tid];
    const int o = o0 + tid;
    tot += ba[o & (T_ - 1)];
    g[o] = 1.f / (1.f + __expf(-tot));
  }
}

// ---------------- finalize: out = g[bt] * x
__global__ __launch_bounds__(128) void finalize_kernel(const float* __restrict__ x,
                                                       const float* __restrict__ g,
                                                       float* __restrict__ out) {
  const int bt = blockIdx.x;
  const float sg = g[bt];
  const f32x4* xp = (const f32x4*)(x + (size_t)bt * D_);
  f32x4* op = (f32x4*)(out + (size_t)bt * D_);
  op[threadIdx.x] = xp[threadIdx.x] * sg;
}

// ---------------- launch
extern "C" void kernel_launch(void* const* d_in, const int* in_sizes, int n_in,
                              void* d_out, int out_size, void* d_ws, size_t ws_size,
                              hipStream_t stream) {
  const float* x     = (const float*)d_in[0];
  const float* W1    = (const float*)d_in[1];
  const float* b1    = (const float*)d_in[2];
  const float* W2    = (const float*)d_in[3];
  const float* b2    = (const float*)d_in[4];
  const float* W3    = (const float*)d_in[5];
  const float* b3    = (const float*)d_in[6];
  const float* gamma = (const float*)d_in[7];
  const float* beta  = (const float*)d_in[8];
  const float* Wa    = (const float*)d_in[9];
  const float* ba    = (const float*)d_in[10];
  float* out = (float*)d_out;

  char* ws = (char*)d_ws;
  // ws layout (17.33 MB total):
  __hip_bfloat16* h1  = (__hip_bfloat16*)(ws + 0);         // 4 MB
  __hip_bfloat16* h2  = (__hip_bfloat16*)(ws + 4194304);   // 4 MB
  float* f            = (float*)(ws + 8388608);            // 8.4 MB
  __hip_bfloat16* Wt1 = (__hip_bfloat16*)(ws + 16777216);  // 256 KB
  __hip_bfloat16* Wt2 = (__hip_bfloat16*)(ws + 17039360);  // 128 KB
  __hip_bfloat16* Wt3 = (__hip_bfloat16*)(ws + 17170432);  // 128 KB
  float* stats        = (float*)(ws + 17301504);           // 256 B
  float* g            = (float*)(ws + 17301760);           // 32 KB
  float* partial      = (float*)(ws + 0);                  // 8.39 MB, aliases h1+h2 (dead by then)
  __hip_bfloat16* e16 = (__hip_bfloat16*)d_out;            // 8 MB of the 16.8 MB out buf (dead before final write)

  convert_wt<<<dim3(T_ / 32, D_ / 32), 256, 0, stream>>>(W1, Wt1, D_, T_);
  convert_wt<<<dim3(T_ / 32, T_ / 32), 256, 0, stream>>>(W2, Wt2, T_, T_);
  convert_wt<<<dim3(T_ / 32, T_ / 32), 256, 0, stream>>>(W3, Wt3, T_, T_);
  ema2_kernel<<<(B_ * (T_ / EMA_CH) * (D_ / 4)) / 128, 128, 0, stream>>>(x, e16);
  // h1 = tanh(e @ W1 + b1)
  mfma_gemm<D_, 0, true><<<dim3(T_ / 128, (B_ * T_) / 128), 256, 0, stream>>>(e16, Wt1, b1, h1, T_);
  // h2 = relu(h1 @ W2 + b2)
  mfma_gemm<T_, 1, true><<<dim3(T_ / 128, (B_ * T_) / 128), 256, 0, stream>>>(h1, Wt2, b2, h2, T_);
  // f = h2 @ W3 + b3  (f32 out, protects the K=65536 reduction)
  mfma_gemm<T_, 2, false><<<dim3(T_ / 128, (B_ * T_) / 128), 256, 0, stream>>>(h2, Wt3, b3, f, T_);
  ln_stats_kernel<<<B_, 1024, 0, stream>>>(f, stats);
  wa_gemm3<<<L_ / WKC, 512, 0, stream>>>(f, Wa, gamma, beta, stats, partial);
  wa_reduce<<<(B_ * T_) / 32, 256, 0, stream>>>(partial, ba, g);
  finalize_kernel<<<B_ * T_, 128, 0, stream>>>(x, g, out);
}

// Round 12
// 208.358 us; speedup vs baseline: 2.2189x; 1.0885x over previous
//
#include <hip/hip_runtime.h>
#include <hip/hip_bf16.h>

// Problem sizes (fixed): B=32, T=256, D=512
#define B_ 32
#define T_ 256
#define D_ 512
#define L_ (T_ * T_)   // 65536

typedef __attribute__((ext_vector_type(8))) short bf16x8;
typedef __attribute__((ext_vector_type(4))) float f32x4;

static __device__ __forceinline__ unsigned short f2bf(float f) {
  __hip_bfloat16 h = __float2bfloat16(f);
  return *reinterpret_cast<unsigned short*>(&h);
}

// ---------------- weight transpose + bf16 convert: W[K][N] f32 -> Wt[N][K] bf16
__global__ __launch_bounds__(256) void convert_wt(const float* __restrict__ W,
                                                  __hip_bfloat16* __restrict__ Wt,
                                                  int K, int N) {
  __shared__ float tile[32][33];
  const int k0 = blockIdx.y * 32, n0 = blockIdx.x * 32;
  const int c = threadIdx.x & 31, r = threadIdx.x >> 5;  // r = 0..7
#pragma unroll
  for (int i = 0; i < 32; i += 8)
    tile[r + i][c] = W[(size_t)(k0 + r + i) * N + n0 + c];
  __syncthreads();
#pragma unroll
  for (int i = 0; i < 32; i += 8)
    Wt[(size_t)(n0 + r + i) * K + k0 + c] = __float2bfloat16(tile[c][r + i]);
}

// ---------------- EMA (both passes fused), chunked-scan version, bf16 output
#define EMA_CH 32
__global__ __launch_bounds__(128) void ema2_kernel(const float* __restrict__ x,
                                                   __hip_bfloat16* __restrict__ e) {
  const int flat = blockIdx.x * 128 + threadIdx.x;  // 32768 threads
  const int d4 = flat & 127;          // float4 group within D
  const int ci = (flat >> 7) & 7;     // chunk index, 8 chunks of 32
  const int b = flat >> 10;
  const double a1d = 0.9, a2d = 0.9 * 1.5;
  const float a1 = (float)a1d, o1 = (float)(1.0 - a1d);
  const float a2 = (float)a2d, o2 = (float)(1.0 - a2d);

  const size_t base = (size_t)b * (T_ * D_) + (size_t)d4 * 4;
  const float* xp = x + base;
  __hip_bfloat16* ep = e + base;

  f32x4 c1, c2;
  const int t0 = ci * EMA_CH;
  int tstart;
  if (ci == 0) {
    const f32x4 xv = *(const f32x4*)xp;
    c1 = xv;
    c2 = xv;
    const f32x4 v = c1 + c2;
    short4 p;
    p.x = (short)f2bf(v.x); p.y = (short)f2bf(v.y);
    p.z = (short)f2bf(v.z); p.w = (short)f2bf(v.w);
    *(short4*)ep = p;
    tstart = 1;
  } else {
    c1 = (f32x4){0.f, 0.f, 0.f, 0.f};
    c2 = (f32x4){0.f, 0.f, 0.f, 0.f};
#pragma unroll 8
    for (int t = t0 - EMA_CH; t < t0; ++t) {  // warm-up, no store
      const f32x4 xv = *(const f32x4*)(xp + (size_t)t * D_);
      c1 = a1 * xv + o1 * c1;
      c2 = a2 * c1 + o2 * c2;
    }
    tstart = t0;
  }
#pragma unroll 8
  for (int t = tstart; t < t0 + EMA_CH; ++t) {  // live steps
    const f32x4 xv = *(const f32x4*)(xp + (size_t)t * D_);
    c1 = a1 * xv + o1 * c1;
    c2 = a2 * c1 + o2 * c2;
    const f32x4 v = c1 + c2;
    short4 p;
    p.x = (short)f2bf(v.x); p.y = (short)f2bf(v.y);
    p.z = (short)f2bf(v.z); p.w = (short)f2bf(v.w);
    *(short4*)(ep + (size_t)t * D_) = p;
  }
}

// ---------------- bf16 MFMA GEMM: C = act(A[M,K] @ Bt[N,K]^T + bias)
template <int K, int ACT, bool OUTBF16>
__global__ __launch_bounds__(256) void mfma_gemm(const __hip_bfloat16* __restrict__ A,
                                                 const __hip_bfloat16* __restrict__ Bt,
                                                 const float* __restrict__ bias,
                                                 void* __restrict__ Cout, int N) {
  __shared__ __align__(16) short As[128 * 32];  // [row][k] bf16
  __shared__ __align__(16) short Bs[128 * 32];  // [col][k] bf16
  const int tid = threadIdx.x;
  const int lane = tid & 63, w = tid >> 6;
  const int wr = w >> 1, wc = w & 1;
  const int rowBase = blockIdx.y * 128, colBase = blockIdx.x * 128;
  const int r = tid >> 2, kb = tid & 3;  // staging coords: 4 threads x 16B = 64B row

  const short* Ag = (const short*)A;
  const short* Bg = (const short*)Bt;

  f32x4 acc[4][4] = {};

  for (int k0 = 0; k0 < K; k0 += 32) {
    __builtin_amdgcn_global_load_lds(
        (const __attribute__((address_space(1))) void*)(Ag + (size_t)(rowBase + r) * K + k0 + kb * 8),
        (__attribute__((address_space(3))) void*)(As + w * 512), 16, 0, 0);
    __builtin_amdgcn_global_load_lds(
        (const __attribute__((address_space(1))) void*)(Ag + (size_t)(rowBase + 64 + r) * K + k0 + kb * 8),
        (__attribute__((address_space(3))) void*)(As + 2048 + w * 512), 16, 0, 0);
    __builtin_amdgcn_global_load_lds(
        (const __attribute__((address_space(1))) void*)(Bg + (size_t)(colBase + r) * K + k0 + kb * 8),
        (__attribute__((address_space(3))) void*)(Bs + w * 512), 16, 0, 0);
    __builtin_amdgcn_global_load_lds(
        (const __attribute__((address_space(1))) void*)(Bg + (size_t)(colBase + 64 + r) * K + k0 + kb * 8),
        (__attribute__((address_space(3))) void*)(Bs + 2048 + w * 512), 16, 0, 0);
    __syncthreads();  // drains vmcnt -> staged data visible

    bf16x8 af[4], bfr[4];
#pragma unroll
    for (int m = 0; m < 4; ++m)
      af[m] = *(const bf16x8*)&As[(wr * 64 + m * 16 + (lane & 15)) * 32 + (lane >> 4) * 8];
#pragma unroll
    for (int n = 0; n < 4; ++n)
      bfr[n] = *(const bf16x8*)&Bs[(wc * 64 + n * 16 + (lane & 15)) * 32 + (lane >> 4) * 8];
#pragma unroll
    for (int m = 0; m < 4; ++m)
#pragma unroll
      for (int n = 0; n < 4; ++n)
        acc[m][n] = __builtin_amdgcn_mfma_f32_16x16x32_bf16(af[m], bfr[n], acc[m][n], 0, 0, 0);
    __syncthreads();
  }

  // epilogue: C/D layout col=lane&15, row=(lane>>4)*4+reg (m89-verified)
  const int orow0 = rowBase + wr * 64 + ((lane >> 4) << 2);
  const int ocol0 = colBase + wc * 64 + (lane & 15);
#pragma unroll
  for (int m = 0; m < 4; ++m)
#pragma unroll
    for (int n = 0; n < 4; ++n) {
      const int gc = ocol0 + n * 16;
      const float bv = bias[gc];
#pragma unroll
      for (int j = 0; j < 4; ++j) {
        const size_t gr = orow0 + m * 16 + j;
        float v = acc[m][n][j] + bv;
        if (ACT == 0) v = tanhf(v);
        if (ACT == 1) v = fmaxf(v, 0.f);
        if (OUTBF16)
          ((__hip_bfloat16*)Cout)[gr * N + gc] = __float2bfloat16(v);
        else
          ((float*)Cout)[gr * N + gc] = v;
      }
    }
}

// ---------------- LayerNorm stats (per b over 65536)
__global__ __launch_bounds__(1024) void ln_stats_kernel(const float* __restrict__ f,
                                                        float* __restrict__ stats) {
  const int b = blockIdx.x;
  const f32x4* fp = (const f32x4*)(f + (size_t)b * L_);
  float s = 0.f, s2 = 0.f;
  for (int i = threadIdx.x; i < L_ / 4; i += 1024) {
    f32x4 v = fp[i];
    s += v.x + v.y + v.z + v.w;
    s2 += v.x * v.x + v.y * v.y + v.z * v.z + v.w * v.w;
  }
#pragma unroll
  for (int off = 32; off; off >>= 1) {
    s += __shfl_down(s, off, 64);
    s2 += __shfl_down(s2, off, 64);
  }
  __shared__ float ls[16], ls2[16];
  const int wid = threadIdx.x >> 6, lane = threadIdx.x & 63;
  if (lane == 0) { ls[wid] = s; ls2[wid] = s2; }
  __syncthreads();
  if (threadIdx.x == 0) {
    float S = 0.f, S2 = 0.f;
#pragma unroll
    for (int i = 0; i < 16; ++i) { S += ls[i]; S2 += ls2[i]; }
    const float mu = S / L_;
    const float var = S2 / L_ - mu * mu;
    stats[b * 2 + 0] = mu;
    stats[b * 2 + 1] = rsqrtf(var + 1e-3f);
  }
}

// ---------------- Wa GEMM v4: concurrency fix for the 51us wa_gemm3.
// Evidence (r9): VALUBusy 15%, HBM 11%, Occ 15% -> latency/ILP-bound.
// Fix both axes: 512 blocks (WKC=128 -> 2-3 blocks/CU) AND unroll 8 (8
// independent Wa f32x4 loads in flight per wave, 8 KB/wave). Partial goes
// bf16 so 512 chunks still fit the 8.39 MB alias region (error ~4e-3 << 0.09).
#define WKC 128
__global__ __launch_bounds__(512) void wa_gemm4(const float* __restrict__ f,
                                                const float* __restrict__ Wa,
                                                const float* __restrict__ gamma,
                                                const float* __restrict__ beta,
                                                const float* __restrict__ stats,
                                                __hip_bfloat16* __restrict__ partial) {
  const int kbidx = blockIdx.x;
  const int k0 = kbidx * WKC;
  const int tid = threadIdx.x, lane = tid & 63, w = tid >> 6;
  const int g = w & 3, h = w >> 2;   // b-group (8 batches), k-half (64 rows)
  __shared__ float fs[WKC][36];      // 18 KB staged LN'd f, transposed
  __shared__ float red[B_ * T_];     // 32 KB cross-half reduce

  // stage LN'd f chunk, transposed; coalesced 128-float runs per b
  for (int l = tid; l < B_ * WKC; l += 512) {
    const int b = l >> 7, kk = l & (WKC - 1);
    const int gk = k0 + kk;
    fs[kk][b] = (f[(size_t)b * L_ + gk] - stats[b * 2]) * stats[b * 2 + 1] * gamma[gk] + beta[gk];
  }
  __syncthreads();

  f32x4 acc[8] = {};
  const int b0 = g * 8;
  const size_t kbase = (size_t)k0 + h * 64;
  for (int kk = 0; kk < 64; kk += 8) {
    f32x4 wv[8];
#pragma unroll
    for (int u = 0; u < 8; ++u)
      wv[u] = *(const f32x4*)&Wa[(kbase + kk + u) * T_ + lane * 4];  // 8 loads in flight
#pragma unroll
    for (int u = 0; u < 8; ++u) {
      const float* frow = &fs[h * 64 + kk + u][b0];
      const f32x4 fA = *(const f32x4*)frow;        // broadcast b128, conflict-free
      const f32x4 fB = *(const f32x4*)(frow + 4);
      acc[0] += wv[u] * fA.x; acc[1] += wv[u] * fA.y;
      acc[2] += wv[u] * fA.z; acc[3] += wv[u] * fA.w;
      acc[4] += wv[u] * fB.x; acc[5] += wv[u] * fB.y;
      acc[6] += wv[u] * fB.z; acc[7] += wv[u] * fB.w;
    }
  }

  // combine k-halves: h=1 parks in LDS, h=0 adds and stores bf16 partial
  if (h == 1) {
#pragma unroll
    for (int bb = 0; bb < 8; ++bb)
      *(f32x4*)&red[(size_t)(b0 + bb) * 256 + lane * 4] = acc[bb];
  }
  __syncthreads();
  if (h == 0) {
#pragma unroll
    for (int bb = 0; bb < 8; ++bb) {
      const f32x4 o = acc[bb] + *(const f32x4*)&red[(size_t)(b0 + bb) * 256 + lane * 4];
      short4 p;
      p.x = (short)f2bf(o.x); p.y = (short)f2bf(o.y);
      p.z = (short)f2bf(o.z); p.w = (short)f2bf(o.w);
      *(short4*)&partial[(size_t)kbidx * (B_ * T_) + (size_t)(b0 + bb) * T_ + lane * 4] = p;
    }
  }
}

// ---------------- reduce bf16 partials over 512 k-chunks, fuse +ba and sigmoid
__global__ __launch_bounds__(256) void wa_reduce(const __hip_bfloat16* __restrict__ partial,
                                                 const float* __restrict__ ba,
                                                 float* __restrict__ g) {
  const int o0 = blockIdx.x * 32;  // 256 blocks x 32 outputs
  const int tid = threadIdx.x, lane = tid & 63, w = tid >> 6;
  const int oo = tid & 31;   // output within block
  const int kg = tid >> 5;   // 0..7: kb-group of 64
  float s = 0.f;
#pragma unroll 8
  for (int i = 0; i < 64; ++i)
    s += __bfloat162float(partial[(size_t)(kg * 64 + i) * (B_ * T_) + o0 + oo]);
  s += __shfl_down(s, 32, 64);  // fold the two kg's within each wave
  __shared__ float red[4][32];
  if ((lane >> 5) == 0) red[w][oo] = s;
  __syncthreads();
  if (tid < 32) {
    float tot = red[0][tid] + red[1][tid] + red[2][tid] + red[3][tid];
    const int o = o0 + tid;
    tot += ba[o & (T_ - 1)];
    g[o] = 1.f / (1.f + __expf(-tot));
  }
}

// ---------------- finalize: out = g[bt] * x
__global__ __launch_bounds__(128) void finalize_kernel(const float* __restrict__ x,
                                                       const float* __restrict__ g,
                                                       float* __restrict__ out) {
  const int bt = blockIdx.x;
  const float sg = g[bt];
  const f32x4* xp = (const f32x4*)(x + (size_t)bt * D_);
  f32x4* op = (f32x4*)(out + (size_t)bt * D_);
  op[threadIdx.x] = xp[threadIdx.x] * sg;
}

// ---------------- launch
extern "C" void kernel_launch(void* const* d_in, const int* in_sizes, int n_in,
                              void* d_out, int out_size, void* d_ws, size_t ws_size,
                              hipStream_t stream) {
  const float* x     = (const float*)d_in[0];
  const float* W1    = (const float*)d_in[1];
  const float* b1    = (const float*)d_in[2];
  const float* W2    = (const float*)d_in[3];
  const float* b2    = (const float*)d_in[4];
  const float* W3    = (const float*)d_in[5];
  const float* b3    = (const float*)d_in[6];
  const float* gamma = (const float*)d_in[7];
  const float* beta  = (const float*)d_in[8];
  const float* Wa    = (const float*)d_in[9];
  const float* ba    = (const float*)d_in[10];
  float* out = (float*)d_out;

  char* ws = (char*)d_ws;
  // ws layout (17.33 MB total):
  __hip_bfloat16* h1  = (__hip_bfloat16*)(ws + 0);         // 4 MB
  __hip_bfloat16* h2  = (__hip_bfloat16*)(ws + 4194304);   // 4 MB
  float* f            = (float*)(ws + 8388608);            // 8.4 MB
  __hip_bfloat16* Wt1 = (__hip_bfloat16*)(ws + 16777216);  // 256 KB
  __hip_bfloat16* Wt2 = (__hip_bfloat16*)(ws + 17039360);  // 128 KB
  __hip_bfloat16* Wt3 = (__hip_bfloat16*)(ws + 17170432);  // 128 KB
  float* stats        = (float*)(ws + 17301504);           // 256 B
  float* g            = (float*)(ws + 17301760);           // 32 KB
  __hip_bfloat16* partial = (__hip_bfloat16*)(ws + 0);     // 512*8192*2 = 8.39 MB, aliases h1+h2 (dead by then)
  __hip_bfloat16* e16 = (__hip_bfloat16*)d_out;            // 8 MB of the 16.8 MB out buf (dead before final write)

  convert_wt<<<dim3(T_ / 32, D_ / 32), 256, 0, stream>>>(W1, Wt1, D_, T_);
  convert_wt<<<dim3(T_ / 32, T_ / 32), 256, 0, stream>>>(W2, Wt2, T_, T_);
  convert_wt<<<dim3(T_ / 32, T_ / 32), 256, 0, stream>>>(W3, Wt3, T_, T_);
  ema2_kernel<<<(B_ * (T_ / EMA_CH) * (D_ / 4)) / 128, 128, 0, stream>>>(x, e16);
  // h1 = tanh(e @ W1 + b1)
  mfma_gemm<D_, 0, true><<<dim3(T_ / 128, (B_ * T_) / 128), 256, 0, stream>>>(e16, Wt1, b1, h1, T_);
  // h2 = relu(h1 @ W2 + b2)
  mfma_gemm<T_, 1, true><<<dim3(T_ / 128, (B_ * T_) / 128), 256, 0, stream>>>(h1, Wt2, b2, h2, T_);
  // f = h2 @ W3 + b3  (f32 out, protects the K=65536 reduction)
  mfma_gemm<T_, 2, false><<<dim3(T_ / 128, (B_ * T_) / 128), 256, 0, stream>>>(h2, Wt3, b3, f, T_);
  ln_stats_kernel<<<B_, 1024, 0, stream>>>(f, stats);
  wa_gemm4<<<L_ / WKC, 512, 0, stream>>>(f, Wa, gamma, beta, stats, partial);
  wa_reduce<<<(B_ * T_) / 32, 256, 0, stream>>>(partial, ba, g);
  finalize_kernel<<<B_ * T_, 128, 0, stream>>>(x, g, out);
}